// Round 8
// baseline (209.866 us; speedup 1.0000x reference)
//
#include <hip/hip_runtime.h>
#include <math.h>

#define N 8192
#define C 10
#define NUM_ITERS 5
#define FBLOCK 256        /* filter block: 4 waves */
#define JCH 16            /* j splits (partial accumulators) */
#define JPB (N / JCH)     /* 512 j's per block = one LDS stage */
#define JT 512            /* j's staged per LDS chunk */
#define IBLK 128          /* i's per filter block: 4 waves x 32 */
#define NIB (N / IBLK)    /* 64 */
#define NG (JPB / 16)     /* 32 groups of 16 j's */
#define LOG2E 1.44269504088896340736f
#define C3 (LOG2E / 64.0f)
#define PROW (JT + 8)     /* padded LDS row for p (f16 elems) */
#define ZOFF (JT * 2)     /* zeroed half4 slot in aj LDS arrays */

typedef _Float16 half8 __attribute__((ext_vector_type(8)));
typedef _Float16 half4 __attribute__((ext_vector_type(4)));
typedef float f32x4 __attribute__((ext_vector_type(4)));

// ws byte offsets:
//   ajs half8[N], ajb half8[N], pf f16[16][N],
//   part float[JCH][20][N], red float[20][N]
#define WS_AJS 0
#define WS_AJB (N * 16)
#define WS_PF  (N * 32)
#define WS_PART (N * 64)
#define WS_RED (N * 64 + (size_t)JCH * 20 * N * 4)

// once per launch: prep augmented features + softmax(unaries) -> pf
__global__ __launch_bounds__(256) void init_kernel(
    const float* __restrict__ unaries, const float* __restrict__ feat,
    half8* __restrict__ ajs, half8* __restrict__ ajb, _Float16* __restrict__ pf) {
    int n = blockIdx.x * 256 + threadIdx.x;
    float f[6];
#pragma unroll
    for (int d = 0; d < 6; ++d) f[d] = feat[d * N + n];
    float h3 = 0.5f * (f[0] * f[0] + f[1] * f[1] + f[2] * f[2]);
    float h6 = h3 + 0.5f * (f[3] * f[3] + f[4] * f[4] + f[5] * f[5]);
    half8 a = {};
    a[0] = (_Float16)(f[0] * C3);
    a[1] = (_Float16)(f[1] * C3);
    a[2] = (_Float16)(f[2] * C3);
    a[6] = (_Float16)(-h3 * C3);
    a[7] = (_Float16)1.0f;
    ajs[n] = a;
    half8 b;
#pragma unroll
    for (int d = 0; d < 6; ++d) b[d] = (_Float16)(f[d] * LOG2E);
    b[6] = (_Float16)(-h6 * LOG2E);
    b[7] = (_Float16)1.0f;
    ajb[n] = b;

    float q[C];
#pragma unroll
    for (int c = 0; c < C; ++c) q[c] = unaries[c * N + n];
    float m = q[0];
#pragma unroll
    for (int c = 1; c < C; ++c) m = fmaxf(m, q[c]);
    float e[C], s = 0.0f;
#pragma unroll
    for (int c = 0; c < C; ++c) {
        e[c] = __builtin_amdgcn_exp2f((q[c] - m) * LOG2E);
        s += e[c];
    }
    float inv = 1.0f / s;
#pragma unroll
    for (int c = 0; c < C; ++c) pf[c * N + n] = (_Float16)(e[c] * inv);
#pragma unroll
    for (int c = C; c < 16; ++c) pf[c * N + n] = (_Float16)0.0f;
}

// red[20][N] = sum_jc part[jc][20][N]  (pure float4 streaming, high MLP)
__global__ __launch_bounds__(256) void reduce_kernel(const float4* __restrict__ part,
                                                     float4* __restrict__ red) {
    int o = blockIdx.x * 256 + threadIdx.x;   // float4 index into [20][N/4]
    float4 r = part[o];
#pragma unroll
    for (int jc = 1; jc < JCH; ++jc) {
        float4 v = part[(size_t)jc * 20 * (N / 4) + o];
        r.x += v.x; r.y += v.y; r.z += v.z; r.w += v.w;
    }
    red[o] = r;
}

// message passing + compatibility + softmax (or final out). Helper-split loads.
__global__ __launch_bounds__(256) void combine_kernel(
    const float* __restrict__ unaries, const float* __restrict__ SW,
    const float* __restrict__ BW, const float* __restrict__ CM,
    const float* __restrict__ red, _Float16* __restrict__ pf,
    float* __restrict__ out, int is_last) {
    __shared__ float sSW[100], sBW[100], sCM[100];
    __shared__ float spl[10][128], bll[10][128], ul[10][128];
    int t = threadIdx.x;
    if (t < 100) { sSW[t] = SW[t]; sBW[t] = BW[t]; sCM[t] = CM[t]; }
    int nl = t & 127;
    int h = t >> 7;
    int n = blockIdx.x * 128 + nl;

    if (h == 0) {
#pragma unroll
        for (int k = 0; k < C; ++k) spl[k][nl] = red[k * N + n];
#pragma unroll
        for (int k = 0; k < 5; ++k) ul[k][nl] = unaries[k * N + n];
    } else {
#pragma unroll
        for (int k = 0; k < C; ++k) bll[k][nl] = red[(C + k) * N + n];
#pragma unroll
        for (int k = 5; k < C; ++k) ul[k][nl] = unaries[k * N + n];
    }
    __syncthreads();

    float q[C];
#pragma unroll
    for (int c = 0; c < C; ++c) {
        float m = 0.0f;
#pragma unroll
        for (int k = 0; k < C; ++k)
            m += sSW[c * C + k] * spl[k][nl] + sBW[c * C + k] * bll[k][nl];
        q[c] = m;   // msg
    }
    float qq[C];
#pragma unroll
    for (int c = 0; c < C; ++c) {
        float pw = 0.0f;
#pragma unroll
        for (int k = 0; k < C; ++k) pw += sCM[c * C + k] * q[k];
        qq[c] = ul[c][nl] - pw;
    }

    if (is_last) {
#pragma unroll
        for (int c = 0; c < 5; ++c) out[(h * 5 + c) * N + n] = qq[h * 5 + c];
    } else {
        float m = qq[0];
#pragma unroll
        for (int c = 1; c < C; ++c) m = fmaxf(m, qq[c]);
        float e[C], s = 0.0f;
#pragma unroll
        for (int c = 0; c < C; ++c) {
            e[c] = __builtin_amdgcn_exp2f((qq[c] - m) * LOG2E);
            s += e[c];
        }
        float inv = 1.0f / s;
#pragma unroll
        for (int c = 0; c < 8; ++c) {
            int row = h * 8 + c;
            float v = (row < C) ? e[row] * inv : 0.0f;
            pf[row * N + n] = (_Float16)v;
        }
    }
}

static __device__ inline half4 expcvt(f32x4 d) {
    half4 r;
    r[0] = (_Float16)__builtin_amdgcn_exp2f(d[0]);
    r[1] = (_Float16)__builtin_amdgcn_exp2f(d[1]);
    r[2] = (_Float16)__builtin_amdgcn_exp2f(d[2]);
    r[3] = (_Float16)__builtin_amdgcn_exp2f(d[3]);
    return r;
}

__global__ __launch_bounds__(FBLOCK, 4) void filter_kernel(
    const float* __restrict__ feat, const half4* __restrict__ ajs,
    const half4* __restrict__ ajb, const _Float16* __restrict__ pf,
    float* __restrict__ part) {
    __shared__ half4 ajs_l[JT * 2 + 2];    //  ~8 KB  [j][h] + zero slot
    __shared__ half4 ajb_l[JT * 2 + 2];    //  ~8 KB
    __shared__ _Float16 p_l[16 * PROW];    // 16.25 KB

    int t = threadIdx.x;
    int ibb = blockIdx.x * IBLK;
    int jc = blockIdx.y;
    int jbase = jc * JPB;

    // ---- stage j-chunk (coalesced float4) ----
    {
        const float4* s0 = (const float4*)(ajs + (size_t)jbase * 2);
        const float4* s1 = (const float4*)(ajb + (size_t)jbase * 2);
        float4* d0 = (float4*)ajs_l;
        float4* d1 = (float4*)ajb_l;
        for (int k = t; k < JT; k += FBLOCK) { d0[k] = s0[k]; d1[k] = s1[k]; }
        const float4* ps = (const float4*)pf;
        float4* pd = (float4*)p_l;
        for (int k = t; k < 16 * (JT / 8); k += FBLOCK) {
            int c = k >> 6, off = k & 63;
            pd[c * (PROW / 8) + off] = ps[c * (N / 8) + (jbase >> 3) + off];
        }
        if (t == 0) {
            const half4 hz = {};
            ajs_l[ZOFF] = hz; ajb_l[ZOFF] = hz;
        }
    }
    __syncthreads();

    int lane = t & 63;
    int w = t >> 6;
    int il = lane & 15;
    int quad = lane >> 4;
    int h = quad & 1;
    bool klo = (quad < 2);
    int i0 = ibb + w * 32;   // wave's 32 i's: subtile0 = i0.., subtile1 = i0+16..

    const half4 hz = {};

    // B1 fragments (i-side aug), K=16 layout: lane holds B[k=quad*4+r][n=il]
    half4 b1s0, b1s1, b1b0, b1b1;
#pragma unroll
    for (int s = 0; s < 2; ++s) {
        int i = i0 + s * 16 + il;
        float g0 = feat[0 * N + i], g1 = feat[1 * N + i], g2 = feat[2 * N + i];
        float g3 = feat[3 * N + i], g4 = feat[4 * N + i], g5 = feat[5 * N + i];
        float h3 = 0.5f * (g0 * g0 + g1 * g1 + g2 * g2);
        float h6 = h3 + 0.5f * (g3 * g3 + g4 * g4 + g5 * g5);
        half4 slo = {(_Float16)g0, (_Float16)g1, (_Float16)g2, (_Float16)0.0f};
        half4 shi = {(_Float16)0.0f, (_Float16)0.0f, (_Float16)1.0f, (_Float16)(-h3 * C3)};
        half4 blo = {(_Float16)g0, (_Float16)g1, (_Float16)g2, (_Float16)g3};
        half4 bhi = {(_Float16)g4, (_Float16)g5, (_Float16)1.0f, (_Float16)(-h6 * LOG2E)};
        half4 vs = klo ? (h ? shi : slo) : hz;
        half4 vb = klo ? (h ? bhi : blo) : hz;
        if (s == 0) { b1s0 = vs; b1b0 = vb; } else { b1s1 = vs; b1b1 = vb; }
    }

    f32x4 as0 = {0.f, 0.f, 0.f, 0.f}, as1 = {0.f, 0.f, 0.f, 0.f};
    f32x4 ab0 = {0.f, 0.f, 0.f, 0.f}, ab1 = {0.f, 0.f, 0.f, 0.f};
    const f32x4 zero = {0.f, 0.f, 0.f, 0.f};

    // group-g fragment offset: aj index or the zeroed slot for k-high lanes
    int offbase = il * 2 + h;
    int poff = il * PROW + quad * 4;

#define MFMA1(sA, bA, e0, e1, e2, e3)                                          \
    e0 = __builtin_amdgcn_mfma_f32_16x16x16f16(sA, b1s0, zero, 0, 0, 0);       \
    e1 = __builtin_amdgcn_mfma_f32_16x16x16f16(sA, b1s1, zero, 0, 0, 0);       \
    e2 = __builtin_amdgcn_mfma_f32_16x16x16f16(bA, b1b0, zero, 0, 0, 0);       \
    e3 = __builtin_amdgcn_mfma_f32_16x16x16f16(bA, b1b1, zero, 0, 0, 0);

#define FIRE(e0, e1, e2, e3, pX)                                               \
    {                                                                          \
        half4 w0 = expcvt(e0), w1 = expcvt(e1), w2 = expcvt(e2), w3 = expcvt(e3); \
        as0 = __builtin_amdgcn_mfma_f32_16x16x16f16(w0, pX, as0, 0, 0, 0);     \
        as1 = __builtin_amdgcn_mfma_f32_16x16x16f16(w1, pX, as1, 0, 0, 0);     \
        ab0 = __builtin_amdgcn_mfma_f32_16x16x16f16(w2, pX, ab0, 0, 0, 0);     \
        ab1 = __builtin_amdgcn_mfma_f32_16x16x16f16(w3, pX, ab1, 0, 0, 0);     \
    }

    // ---- software-pipelined main loop: mfma1(g+1) overlaps exp+mfma2(g) ----
    f32x4 e0, e1, e2, e3, f0, f1, f2, f3;
    int offA = klo ? (0 * 32 + offbase) : ZOFF;
    half4 sA = ajs_l[offA], bA = ajb_l[offA];
    half4 pA = *(const half4*)&p_l[poff + 0 * 16];
    MFMA1(sA, bA, e0, e1, e2, e3)

#pragma unroll 1
    for (int g = 0; g < NG - 2; g += 2) {
        int offB = klo ? ((g + 1) * 32 + offbase) : ZOFF;
        half4 sB = ajs_l[offB], bB = ajb_l[offB];
        half4 pB = *(const half4*)&p_l[poff + (g + 1) * 16];
        MFMA1(sB, bB, f0, f1, f2, f3)
        FIRE(e0, e1, e2, e3, pA)
        int offA2 = klo ? ((g + 2) * 32 + offbase) : ZOFF;
        sA = ajs_l[offA2]; bA = ajb_l[offA2];
        pA = *(const half4*)&p_l[poff + (g + 2) * 16];
        MFMA1(sA, bA, e0, e1, e2, e3)
        FIRE(f0, f1, f2, f3, pB)
    }
    // tail: groups NG-2 (in e/pA) and NG-1
    {
        int offB = klo ? ((NG - 1) * 32 + offbase) : ZOFF;
        half4 sB = ajs_l[offB], bB = ajb_l[offB];
        half4 pB = *(const half4*)&p_l[poff + (NG - 1) * 16];
        MFMA1(sB, bB, f0, f1, f2, f3)
        FIRE(e0, e1, e2, e3, pA)
        FIRE(f0, f1, f2, f3, pB)
    }
#undef MFMA1
#undef FIRE

    // writeout: plain stores to this j-split's private partial slice
    if (il < C) {
        float* psp = part + ((size_t)jc * 20 + il) * N;
        float* pbl = part + ((size_t)jc * 20 + C + il) * N;
        int ia = i0 + quad * 4;
#pragma unroll
        for (int r = 0; r < 4; ++r) {
            psp[ia + r]      = as0[r];
            psp[ia + 16 + r] = as1[r];
            pbl[ia + r]      = ab0[r];
            pbl[ia + 16 + r] = ab1[r];
        }
    }
}

extern "C" void kernel_launch(void* const* d_in, const int* in_sizes, int n_in,
                              void* d_out, int out_size, void* d_ws, size_t ws_size,
                              hipStream_t stream) {
    const float* unaries = (const float*)d_in[0];   // [10, 8192]
    const float* feat    = (const float*)d_in[1];   // [6, 8192]
    const float* SW      = (const float*)d_in[2];   // [10,10]
    const float* BW      = (const float*)d_in[3];   // [10,10]
    const float* CM      = (const float*)d_in[4];   // [10,10]
    float* out = (float*)d_out;

    char* ws = (char*)d_ws;
    half8* ajs    = (half8*)(ws + WS_AJS);
    half8* ajb    = (half8*)(ws + WS_AJB);
    _Float16* pf  = (_Float16*)(ws + WS_PF);
    float* part   = (float*)(ws + WS_PART);
    float* red    = (float*)(ws + WS_RED);

    init_kernel<<<N / 256, 256, 0, stream>>>(unaries, feat, ajs, ajb, pf);
    for (int it = 1; it <= NUM_ITERS; ++it) {
        filter_kernel<<<dim3(NIB, JCH), FBLOCK, 0, stream>>>(feat, (const half4*)ajs,
                                                             (const half4*)ajb, pf, part);
        reduce_kernel<<<20 * N / 4 / 256, 256, 0, stream>>>((const float4*)part,
                                                            (float4*)red);
        combine_kernel<<<N / 128, 256, 0, stream>>>(unaries, SW, BW, CM, red, pf, out,
                                                    it == NUM_ITERS ? 1 : 0);
    }
}